// Round 4
// baseline (7237.240 us; speedup 1.0000x reference)
//
#include <hip/hip_runtime.h>
#include <hip/hip_bf16.h>

#define BS   2
#define PP   512
#define NN   2048
#define DD   768
#define HH   12
#define HD   64
#define RTOT 2560   // P + N rows per batch
#define QKVC 2304   // 3*D

__device__ __forceinline__ float bf2f(unsigned short x) {
    union { unsigned u; float f; } c; c.u = ((unsigned)x) << 16; return c.f;
}

// Runtime-dtype loads (f32 vs bf16). Branch is wave-uniform.
__device__ __forceinline__ float4 load4(const void* p, size_t i, bool f32) {
    if (f32) return *(const float4*)((const float*)p + i);
    ushort4 u = *(const ushort4*)((const unsigned short*)p + i);
    return make_float4(bf2f(u.x), bf2f(u.y), bf2f(u.z), bf2f(u.w));
}
__device__ __forceinline__ float load1(const void* p, size_t i, bool f32) {
    return f32 ? ((const float*)p)[i] : bf2f(((const unsigned short*)p)[i]);
}

// Mask read with runtime type: 0 = int32, 1 = packed u8, 2 = float32
__device__ __forceinline__ bool mask_at(const void* m, int idx, int mtype) {
    if (mtype == 2) return ((const float*)m)[idx] != 0.0f;
    if (mtype == 1) return ((const unsigned char*)m)[idx] != 0;
    return ((const int*)m)[idx] != 0;
}

__device__ __forceinline__ void store_out(float* p, size_t i, float v) { p[i] = v; }
__device__ __forceinline__ void store_out(__hip_bfloat16* p, size_t i, float v) {
    p[i] = __float2bfloat16(v);
}

// ---------------------------------------------------------------------------
// Runtime dtype detection (graph-safe, device-only).
// flags[0] = 1 if float inputs are f32 (else bf16)   [round-1/2 A/B proved f32]
// flags[1] = mask type: 0 int32, 1 packed u8, 2 float32  [rounds 2/3 proved int32]
// ---------------------------------------------------------------------------
__global__ void detect_kernel(const void* __restrict__ w,
                              const void* __restrict__ mask,
                              int* __restrict__ flags) {
    __shared__ int s_f32, s_fmask, s_bmask;
    if (threadIdx.x == 0) { s_f32 = 0; s_fmask = 0; s_bmask = 0; }
    __syncthreads();
    const unsigned short* u = (const unsigned short*)w;
    int bad = 0;
    for (int i = threadIdx.x * 2; i < 65536; i += 512) {
        float v = bf2f(u[i]);
        if (!(fabsf(v) <= 2.0f)) bad = 1;   // NaN also lands here
    }
    if (bad) atomicOr(&s_f32, 1);

    const unsigned* mw = (const unsigned*)mask;
    int fm = 0, bm = 0;
    for (int i = threadIdx.x; i < 256; i += 256) {
        unsigned v = mw[i];
        if (v == 0x3F800000u) fm = 1;
        else if ((v & 0xFFFFFF00u) != 0u) bm = 1;
    }
    if (fm) atomicOr(&s_fmask, 1);
    if (bm) atomicOr(&s_bmask, 1);
    __syncthreads();
    if (threadIdx.x == 0) {
        flags[0] = s_f32;
        flags[1] = s_fmask ? 2 : (s_bmask ? 1 : 0);
    }
}

// ---------------------------------------------------------------------------
// Generic 64x64-tile GEMM, runtime-dtype in, f32 accum.  K = 768.
// MODE 0: A = virtual concat [xq(2048); xs(512)] per batch (raw dtype),
//         out = fullqkv (bf16 ws)
// MODE 1: A = attn buffer (bf16 ws), out = d_out (float32!) w/ split mapping
// ---------------------------------------------------------------------------
template<int MODE, int NCOL, typename OutT>
__global__ __launch_bounds__(256) void gemm_kernel(
    const void* __restrict__ A0,
    const void* __restrict__ A1,
    const void* __restrict__ W,      // [768, NCOL] row-major, raw dtype
    const void* __restrict__ bias,   // [NCOL], raw dtype
    const int* __restrict__ flags,
    OutT* __restrict__ out)
{
    const bool f32 = flags[0] != 0;

    alignas(16) __shared__ float As[16][68];
    alignas(16) __shared__ float Bsh[16][68];
    const int tid  = threadIdx.x;
    const int row0 = blockIdx.y * 64;
    const int col0 = blockIdx.x * 64;
    const int ty = tid >> 4;      // 0..15
    const int tx = tid & 15;      // 0..15

    // A staging: each thread loads 4 consecutive k of one row
    const int a_row = tid >> 2;          // 0..63
    const int a_k4  = (tid & 3) * 4;     // 0,4,8,12
    const int grow  = row0 + a_row;
    const void* abase; size_t aoff; bool af32;
    if (MODE == 0) {
        int b = grow / RTOT, r = grow % RTOT;
        if (r < NN) { abase = A0; aoff = (size_t)(b * NN + r) * DD; }
        else        { abase = A1; aoff = (size_t)(b * PP + (r - NN)) * DD; }
        af32 = f32;
    } else {
        abase = A0; aoff = (size_t)grow * DD; af32 = false;
    }
    // B staging indices
    const int b_k  = tid >> 4;           // 0..15
    const int b_n4 = (tid & 15) * 4;     // 0..60

    float acc[4][4] = {};

    for (int k0 = 0; k0 < DD; k0 += 16) {
        float4 fa = load4(abase, aoff + k0 + a_k4, af32);
        As[a_k4 + 0][a_row] = fa.x;
        As[a_k4 + 1][a_row] = fa.y;
        As[a_k4 + 2][a_row] = fa.z;
        As[a_k4 + 3][a_row] = fa.w;

        float4 fb = load4(W, (size_t)(k0 + b_k) * NCOL + col0 + b_n4, f32);
        *(float4*)&Bsh[b_k][b_n4] = fb;

        __syncthreads();
        #pragma unroll
        for (int kk = 0; kk < 16; kk++) {
            float4 av = *(const float4*)&As[kk][ty * 4];
            float4 bv = *(const float4*)&Bsh[kk][tx * 4];
            float a_[4] = {av.x, av.y, av.z, av.w};
            float b_[4] = {bv.x, bv.y, bv.z, bv.w};
            #pragma unroll
            for (int i = 0; i < 4; i++)
                #pragma unroll
                for (int j = 0; j < 4; j++)
                    acc[i][j] += a_[i] * b_[j];
        }
        __syncthreads();
    }

    #pragma unroll
    for (int i = 0; i < 4; i++) {
        int gr = row0 + ty * 4 + i;
        #pragma unroll
        for (int j = 0; j < 4; j++) {
            int gc = col0 + tx * 4 + j;
            float v = acc[i][j] + load1(bias, gc, f32);
            if (MODE == 0) {
                store_out(out, (size_t)gr * NCOL + gc, v);
            } else {
                int b = gr / RTOT, r = gr % RTOT;
                size_t dst = (r < PP)
                    ? ((size_t)(b * PP + r) * DD + gc)
                    : ((size_t)BS * PP * DD + (size_t)(b * NN + (r - PP)) * DD + gc);
                store_out(out, dst, v);
            }
        }
    }
}

// ---------------------------------------------------------------------------
// Attention: one block (256 threads) per (b, h, query row).
// MODE 0 = cross: queries = fullqkv rows 512..2559, keys/vals = rows 0..2559
// MODE 1 = self : queries = rows 0..511, keys/vals = rows 0..511, scrambled out
// Mask applies to key positions m < 512 in both modes.
// ---------------------------------------------------------------------------
template<int MODE>
__global__ __launch_bounds__(256) void attn_kernel(
    const __hip_bfloat16* __restrict__ qkv,  // [BS*2560, 2304] (ws, bf16)
    const void* __restrict__ mask,           // [BS, 512] runtime type
    const int* __restrict__ flags,
    __hip_bfloat16* __restrict__ attn_out)   // [BS*2560, 768] (ws, bf16)
{
    constexpr int NQ   = (MODE == 0) ? NN : PP;
    constexpr int NK   = (MODE == 0) ? RTOT : PP;
    constexpr int QOFF = (MODE == 0) ? PP : 0;

    __shared__ float qs[HD];
    __shared__ float sc[NK];
    __shared__ float red[256];

    const int mtype = flags[1];
    const int bid = blockIdx.x;
    const int n = bid % NQ;
    const int h = (bid / NQ) % HH;
    const int b = bid / (NQ * HH);
    const int tid = threadIdx.x;

    if (tid < HD) {
        qs[tid] = __bfloat162float(
            qkv[(size_t)(b * RTOT + QOFF + n) * QKVC + h * HD + tid]);
    }
    __syncthreads();

    // -------- scores --------
    float lmax = -1e30f;
    for (int m = tid; m < NK; m += 256) {
        const unsigned short* kp =
            (const unsigned short*)(qkv + (size_t)(b * RTOT + m) * QKVC + DD + h * HD);
        float s = 0.f;
        #pragma unroll
        for (int j = 0; j < HD / 4; j++) {
            ushort4 u = ((const ushort4*)kp)[j];
            s += qs[4*j+0] * bf2f(u.x) + qs[4*j+1] * bf2f(u.y)
               + qs[4*j+2] * bf2f(u.z) + qs[4*j+3] * bf2f(u.w);
        }
        bool msk = (m < PP) && mask_at(mask, b * PP + m, mtype);
        s = msk ? -1e30f : s * 0.125f;
        sc[m] = s;
        lmax = fmaxf(lmax, s);
    }

    // -------- max reduce --------
    red[tid] = lmax; __syncthreads();
    for (int off = 128; off > 0; off >>= 1) {
        if (tid < off) red[tid] = fmaxf(red[tid], red[tid + off]);
        __syncthreads();
    }
    float mx = red[0];
    __syncthreads();

    // -------- exp + sum reduce --------
    float lsum = 0.f;
    for (int m = tid; m < NK; m += 256) {
        float e = __expf(sc[m] - mx);
        sc[m] = e;
        lsum += e;
    }
    red[tid] = lsum; __syncthreads();
    for (int off = 128; off > 0; off >>= 1) {
        if (tid < off) red[tid] += red[tid + off];
        __syncthreads();
    }
    float inv = 1.0f / red[0];
    __syncthreads();

    // -------- P @ V --------
    const int dd = tid & 63;
    const int g  = tid >> 6;
    float acc = 0.f;
    for (int m = g; m < NK; m += 4) {
        acc += sc[m] * bf2f(((const unsigned short*)qkv)
                  [(size_t)(b * RTOT + m) * QKVC + 2 * DD + h * HD + dd]);
    }
    red[tid] = acc; __syncthreads();
    if (tid < 64) {
        float r = (red[tid] + red[tid + 64] + red[tid + 128] + red[tid + 192]) * inv;
        __hip_bfloat16 hv = __float2bfloat16(r);
        if (MODE == 0) {
            attn_out[(size_t)(b * RTOT + PP + n) * DD + h * HD + tid] = hv;
        } else {
            // scrambled: f = h*(HD*PP) + dd*PP + p ; (i,j) = (f/768, f%768)
            int f = h * (HD * PP) + tid * PP + n;
            int i = f / DD, j = f % DD;
            attn_out[(size_t)(b * RTOT + i) * DD + j] = hv;
        }
    }
}

// ---------------------------------------------------------------------------
extern "C" void kernel_launch(void* const* d_in, const int* in_sizes, int n_in,
                              void* d_out, int out_size, void* d_ws, size_t ws_size,
                              hipStream_t stream) {
    // Map inputs by unique element counts (immune to ordering surprises).
    const void *xs = nullptr, *xq = nullptr, *mask = nullptr,
               *qkv_w = nullptr, *qkv_b = nullptr, *proj_w = nullptr, *proj_b = nullptr;
    for (int i = 0; i < n_in; i++) {
        switch (in_sizes[i]) {
            case BS * PP * DD:   xs     = d_in[i]; break;  // 786432
            case BS * NN * DD:   xq     = d_in[i]; break;  // 3145728
            case BS * PP:        mask   = d_in[i]; break;  // 1024
            case DD * QKVC:      qkv_w  = d_in[i]; break;  // 1769472
            case QKVC:           qkv_b  = d_in[i]; break;  // 2304
            case DD * DD:        proj_w = d_in[i]; break;  // 589824
            case DD:             proj_b = d_in[i]; break;  // 768
        }
    }
    // Fallback to dict order if any size failed to match.
    if (!xs || !xq || !mask || !qkv_w || !qkv_b || !proj_w || !proj_b) {
        xs = d_in[0]; xq = d_in[1]; mask = d_in[2];
        qkv_w = d_in[3]; qkv_b = d_in[4]; proj_w = d_in[5]; proj_b = d_in[6];
    }

    float* out = (float*)d_out;   // reference output dtype is float32

    int* flags = (int*)d_ws;
    __hip_bfloat16* fullqkv = (__hip_bfloat16*)((char*)d_ws + 256); // [BS*2560, 2304]
    __hip_bfloat16* attn    = fullqkv + (size_t)BS * RTOT * QKVC;   // [BS*2560, 768]

    // 0) runtime dtype detection (graph-safe, device-only)
    detect_kernel<<<1, 256, 0, stream>>>(qkv_w, mask, flags);

    // 1) fullqkv = concat([xq, xs]) @ qkv_w + qkv_b
    gemm_kernel<0, QKVC, __hip_bfloat16>
        <<<dim3(QKVC / 64, BS * RTOT / 64), 256, 0, stream>>>(
        xq, xs, qkv_w, qkv_b, flags, fullqkv);

    // 2) cross attention  -> attn rows 512..2559
    attn_kernel<0><<<BS * HH * NN, 256, 0, stream>>>(fullqkv, mask, flags, attn);

    // 3) self attention (scrambled) -> attn rows 0..511
    attn_kernel<1><<<BS * HH * PP, 256, 0, stream>>>(fullqkv, mask, flags, attn);

    // 4) out = attn @ proj_w + proj_b (float32 out), split-store into d_out
    gemm_kernel<1, DD, float>
        <<<dim3(DD / 64, BS * RTOT / 64), 256, 0, stream>>>(
        attn, nullptr, proj_w, proj_b, flags, out);
}